// Round 15
// baseline (164.303 us; speedup 1.0000x reference)
//
#include <hip/hip_runtime.h>

#define N_NODES 20000
#define E_EDGES 320000
#define EN_TOT  (E_EDGES + N_NODES)   // edges + self loops = 340000
#define IN_DIM  512
#define H1      2
#define C1      128
#define HC1     256                    // H1*C1
#define OUT_DIM 64

typedef __attribute__((ext_vector_type(8))) short short8;
typedef __attribute__((ext_vector_type(4))) float f32x4;
typedef __attribute__((ext_vector_type(2))) float f32x2;

__device__ __forceinline__ unsigned short f2bf(float f) {
  unsigned u = __float_as_uint(f);
  u += 0x7fffu + ((u >> 16) & 1u);    // RNE
  return (unsigned short)(u >> 16);
}
__device__ __forceinline__ float bf2f(unsigned short s) {
  return __uint_as_float(((unsigned)s) << 16);
}
__device__ __forceinline__ f32x2 bfpair(unsigned u) {
  f32x2 r;
  r.x = __uint_as_float(u << 16);
  r.y = __uint_as_float(u & 0xffff0000u);
  return r;
}
__device__ __forceinline__ f32x2 vabs2(f32x2 v) {
  f32x2 r;
  r.x = __uint_as_float(__float_as_uint(v.x) & 0x7fffffffu);
  r.y = __uint_as_float(__float_as_uint(v.y) & 0x7fffffffu);
  return r;
}
__device__ __forceinline__ f32x2 vfma2(f32x2 a, f32x2 b, f32x2 c) {
  return __builtin_elementwise_fma(a, b, c);
}
__device__ __forceinline__ f32x2 vbc2(float s) { f32x2 r; r.x = s; r.y = s; return r; }

// VALU-speed cross-lane add via DPP (within 16-lane rows). All 64 lanes active.
#define DPP_XOR1 0xB1    // quad_perm(1,0,3,2)
#define DPP_XOR2 0x4E    // quad_perm(2,3,0,1)
#define DPP_HM   0x141   // row_half_mirror (lane^7 within 8)
#define DPP_M    0x140   // row_mirror (lane^15 within 16)
template<int CTRL>
__device__ __forceinline__ float dpp_add(float v) {
  return v + __int_as_float(__builtin_amdgcn_update_dpp(
      0, __float_as_int(v), CTRL, 0xF, 0xF, true));
}

// async global->LDS, 16B per lane; LDS dest = wave-uniform base + lane*16 (linear)
__device__ __forceinline__ void gl_lds16(const void* g, void* l) {
  __builtin_amdgcn_global_load_lds((const __attribute__((address_space(1))) void*)g,
                                   (__attribute__((address_space(3))) void*)l, 16, 0, 0);
}

// ---------- merged prep: stats interleaved among xconv (1:8), then wprep ----------
#define STATS_BLOCKS 1250           // 320000 edges / 256
#define XCONV_BLOCKS 10000          // 2,560,000 float4 / 256 threads
#define PREP_IL (STATS_BLOCKS * 9)  // 11250 interleaved blocks
__global__ void prep_kernel(const int* __restrict__ dst, const float* __restrict__ eattr,
                            unsigned long long* __restrict__ pk,
                            const float* __restrict__ x, unsigned short* __restrict__ xb,
                            const float* __restrict__ W1l, const float* __restrict__ W1r,
                            const float* __restrict__ b1l, const float* __restrict__ b1r,
                            unsigned short* __restrict__ W1T, float* __restrict__ bcat1,
                            const float* __restrict__ W2l, const float* __restrict__ W2r,
                            const float* __restrict__ b2l, const float* __restrict__ b2r,
                            unsigned short* __restrict__ W2T, float* __restrict__ bcat2) {
  int bid = blockIdx.x;
  if (bid < PREP_IL) {
    int phase = bid % 9;
    if (phase == 8) {
      int e = (bid / 9) * 256 + threadIdx.x;
      if (e < E_EDGES) {
        int dd = dst[e];
        unsigned long long v = (1ull << 40) |
            (unsigned long long)(unsigned)(eattr[e] * 16777216.0f);
        atomicAdd(&pk[dd], v);
      }
    } else {
      int i = ((bid / 9) * 8 + phase) * 256 + threadIdx.x;   // < 2,560,000 float4s
      float4 v = *reinterpret_cast<const float4*>(x + (size_t)i * 4);
      ushort4 o;
      o.x = f2bf(v.x); o.y = f2bf(v.y); o.z = f2bf(v.z); o.w = f2bf(v.w);
      *reinterpret_cast<ushort4*>(xb + (size_t)i * 4) = o;
    }
  } else {
    int idx = (bid - PREP_IL) * 256 + threadIdx.x;
    const int B1 = 512 * 512;
    if (idx < B1) {
      int n = idx >> 9, k = idx & 511;
      const float* W = (n < 256) ? W1l : W1r;
      int nn = n & 255;
      W1T[idx] = f2bf(W[(size_t)k * 256 + nn]);
      if (k == 0) bcat1[n] = (n < 256) ? b1l[nn] : b1r[nn];
    } else if (idx < B1 + 128 * 256) {
      int t = idx - B1;
      int n = t >> 8, k = t & 255;
      const float* W = (n < 64) ? W2l : W2r;
      int nn = n & 63;
      W2T[t] = f2bf(W[(size_t)k * 64 + nn]);
      if (k == 0) bcat2[n] = (n < 64) ? b2l[nn] : b2r[nn];
    }
  }
}

// ---------- exclusive scan over row lengths (deg+1), single block ----------
__global__ void scan_kernel(const unsigned long long* __restrict__ pk, int* __restrict__ offs) {
  __shared__ int psum[1024];
  const int T = 1024;
  int tid = threadIdx.x;
  const int per = (N_NODES + T - 1) / T;
  int base = tid * per;
  int s = 0;
  for (int i = 0; i < per; ++i) {
    int n = base + i;
    if (n < N_NODES) s += (int)(pk[n] >> 40) + 1;
  }
  psum[tid] = s;
  __syncthreads();
  for (int off = 1; off < T; off <<= 1) {
    int v = (tid >= off) ? psum[tid - off] : 0;
    __syncthreads();
    psum[tid] += v;
    __syncthreads();
  }
  int run = (tid > 0) ? psum[tid - 1] : 0;
  for (int i = 0; i < per; ++i) {
    int n = base + i;
    if (n < N_NODES) {
      offs[n] = run;
      run += (int)(pk[n] >> 40) + 1;
    }
  }
  if (tid == T - 1) offs[N_NODES] = run;
}

// ---------- merged CSR fill + layer-1 GEMM (128x128), interleaved; global_load_lds ----------
// LDS layout: [m][kbs] linear; slot (m,kbs) holds global chunk kb = kbs ^ (m&7).
#define CSR_BLOCKS  1329   // ceil(340000/256)
#define GEMM_BLOCKS 628    // 157 * 4
__global__ __launch_bounds__(256) void csr_gemm1_kernel(
    const int* __restrict__ src, const int* __restrict__ dst, const float* __restrict__ eattr,
    const int* __restrict__ offs, unsigned long long* __restrict__ pk,
    int2* __restrict__ csr,
    const unsigned short* __restrict__ A,    // xb [M][512] bf16
    const unsigned short* __restrict__ BT,   // W1T [512][512] bf16
    const float* __restrict__ bias, unsigned short* __restrict__ C) {
  constexpr int BK = 64;
  __shared__ short8 AsV[128 * 8];   // 16 KB
  __shared__ short8 BsV[128 * 8];   // 16 KB
  const int bid = blockIdx.x;
  bool is_gemm;
  int sub;
  if (bid < 2 * GEMM_BLOCKS) { is_gemm = !(bid & 1); sub = bid >> 1; }
  else                       { is_gemm = false; sub = GEMM_BLOCKS + (bid - 2 * GEMM_BLOCKS); }
  if (!is_gemm) {
    int t = sub * 256 + threadIdx.x;
    if (t < N_NODES) {
      unsigned long long v = pk[t];   // low 40 bits (asum) never touched by decrements
      float sum = (float)(v & 0xFFFFFFFFFFull) * (1.0f / 16777216.0f);
      int deg = offs[t + 1] - offs[t] - 1;
      float la = sum / fmaxf((float)deg, 1.0f);
      csr[offs[t]] = make_int2(t, __float_as_int(la));
    } else if (t < N_NODES + E_EDGES) {
      int e = t - N_NODES;
      int dd = dst[e];
      unsigned long long old = atomicAdd(&pk[dd], (unsigned long long)(-(1ll << 40)));
      int p = offs[dd] + (int)(old >> 40);   // deg, deg-1, ..., 1
      csr[p] = make_int2(src[e], __float_as_int(eattr[e]));
    }
    return;
  }
  // ---- gemm part: M=N_NODES, K=512, N=512, BM=128, BN=128 ----
  const int g = sub;
  const int bm = (g >> 2) * 128;
  const int bn = (g & 3) * 128;
  constexpr int K = 512, N = 512, M = N_NODES;
  const int tid = threadIdx.x;
  const int lane = tid & 63;
  const int wave = tid >> 6;
  const int wr = wave >> 1, wc = wave & 1;
  const int lrow = lane & 15, lk = lane >> 4;

  f32x4 acc[4][4] = {};

  for (int k0 = 0; k0 < K; k0 += BK) {
#pragma unroll
    for (int i = 0; i < 4; ++i) {
      int c = tid + i * 256;
      int m = c >> 3, kbs = c & 7;
      int kb = kbs ^ (m & 7);
      int gr = bm + m;
      if (gr < M)
        gl_lds16(A + (size_t)gr * K + k0 + kb * 8, &AsV[c]);
    }
#pragma unroll
    for (int i = 0; i < 4; ++i) {
      int c = tid + i * 256;
      int n = c >> 3, kbs = c & 7;
      int kb = kbs ^ (n & 7);
      gl_lds16(BT + (size_t)(bn + n) * K + k0 + kb * 8, &BsV[c]);
    }
    __syncthreads();
#pragma unroll
    for (int ks = 0; ks < 2; ++ks) {
      int kb = ks * 4 + lk;
      short8 a[4], b[4];
#pragma unroll
      for (int mf = 0; mf < 4; ++mf) {
        int r = wr * 64 + mf * 16 + lrow;
        a[mf] = AsV[r * 8 + (kb ^ (r & 7))];
      }
#pragma unroll
      for (int nf = 0; nf < 4; ++nf) {
        int n = wc * 64 + nf * 16 + lrow;
        b[nf] = BsV[n * 8 + (kb ^ (n & 7))];
      }
#pragma unroll
      for (int mf = 0; mf < 4; ++mf)
#pragma unroll
        for (int nf = 0; nf < 4; ++nf)
          acc[mf][nf] = __builtin_amdgcn_mfma_f32_16x16x32_bf16(a[mf], b[nf], acc[mf][nf], 0, 0, 0);
    }
    __syncthreads();
  }
#pragma unroll
  for (int mf = 0; mf < 4; ++mf) {
#pragma unroll
    for (int r = 0; r < 4; ++r) {
      int row = bm + wr * 64 + mf * 16 + (lane >> 4) * 4 + r;
      if (row >= M) continue;
#pragma unroll
      for (int nf = 0; nf < 4; ++nf) {
        int col = bn + wc * 64 + nf * 16 + (lane & 15);
        C[(size_t)row * N + col] = f2bf(acc[mf][nf][r] + bias[col]);
      }
    }
  }
}

// ---------- templated bf16 MFMA GEMM (layer 2), global_load_lds staging ----------
template<int BM, int BN>
__global__ __launch_bounds__(256) void gemm_tile_kernel(
    const unsigned short* __restrict__ A,   // [M][K] bf16
    const unsigned short* __restrict__ BT,  // [N][K] bf16
    const float* __restrict__ bias, unsigned short* __restrict__ C,
    int M, int K, int N) {
  constexpr int BK = 64;
  constexpr int MF = BM / 32;
  constexpr int NF = BN / 32;
  __shared__ short8 AsV[BM * 8];
  __shared__ short8 BsV[BN * 8];
  const int bm = blockIdx.x * BM;
  const int bn = blockIdx.y * BN;
  const int tid = threadIdx.x;
  const int lane = tid & 63;
  const int wave = tid >> 6;
  const int wr = wave >> 1, wc = wave & 1;
  const int lrow = lane & 15, lk = lane >> 4;

  f32x4 acc[MF][NF] = {};

  for (int k0 = 0; k0 < K; k0 += BK) {
#pragma unroll
    for (int i = 0; i < BM / 32; ++i) {
      int c = tid + i * 256;
      int m = c >> 3, kbs = c & 7;
      int kb = kbs ^ (m & 7);
      int gr = bm + m;
      if (gr < M)
        gl_lds16(A + (size_t)gr * K + k0 + kb * 8, &AsV[c]);
    }
#pragma unroll
    for (int i = 0; i < BN / 32; ++i) {
      int c = tid + i * 256;
      int n = c >> 3, kbs = c & 7;
      int kb = kbs ^ (n & 7);
      gl_lds16(BT + (size_t)(bn + n) * K + k0 + kb * 8, &BsV[c]);
    }
    __syncthreads();
#pragma unroll
    for (int ks = 0; ks < 2; ++ks) {
      int kb = ks * 4 + lk;
      short8 a[MF], b[NF];
#pragma unroll
      for (int mf = 0; mf < MF; ++mf) {
        int r = wr * (BM / 2) + mf * 16 + lrow;
        a[mf] = AsV[r * 8 + (kb ^ (r & 7))];
      }
#pragma unroll
      for (int nf = 0; nf < NF; ++nf) {
        int n = wc * (BN / 2) + nf * 16 + lrow;
        b[nf] = BsV[n * 8 + (kb ^ (n & 7))];
      }
#pragma unroll
      for (int mf = 0; mf < MF; ++mf)
#pragma unroll
        for (int nf = 0; nf < NF; ++nf)
          acc[mf][nf] = __builtin_amdgcn_mfma_f32_16x16x32_bf16(a[mf], b[nf], acc[mf][nf], 0, 0, 0);
    }
    __syncthreads();
  }
#pragma unroll
  for (int mf = 0; mf < MF; ++mf) {
#pragma unroll
    for (int r = 0; r < 4; ++r) {
      int row = bm + wr * (BM / 2) + mf * 16 + (lane >> 4) * 4 + r;
      if (row >= M) continue;
#pragma unroll
      for (int nf = 0; nf < NF; ++nf) {
        int col = bn + wc * (BN / 2) + nf * 16 + (lane & 15);
        C[(size_t)row * N + col] = f2bf(acc[mf][nf][r] + bias[col]);
      }
    }
  }
}

// ---------- fused layer 1: wave/node, 4-edge batch, DPP reductions, dual state ----------
// xc row: [xl(256) | xr(256)]; lanes 0-31 = head0, 32-63 = head1; 4 ch/lane
__global__ __launch_bounds__(256) void fused1_kernel(
    const int* __restrict__ offs, const int2* __restrict__ csr,
    const unsigned short* __restrict__ xc, const float* __restrict__ We,
    const float* __restrict__ att, const float* __restrict__ bias,
    unsigned short* __restrict__ hout) {
  const int wid = threadIdx.x >> 6, lane = threadIdx.x & 63;
  const int d = blockIdx.x * 4 + wid;
  if (d >= N_NODES) return;
  const int c4 = lane * 4;
  uint2 urr = *reinterpret_cast<const uint2*>(xc + (size_t)d * 512 + 256 + c4);
  const f32x2 xr01 = bfpair(urr.x), xr23 = bfpair(urr.y);
  float4 vef = *reinterpret_cast<const float4*>(We + c4);
  float4 vaf = *reinterpret_cast<const float4*>(att + c4);
  f32x2 ve01; ve01.x = vef.x; ve01.y = vef.y;
  f32x2 ve23; ve23.x = vef.z; ve23.y = vef.w;
  f32x2 c101; c101.x = 0.6f * vaf.x; c101.y = 0.6f * vaf.y;
  f32x2 c123; c123.x = 0.6f * vaf.z; c123.y = 0.6f * vaf.w;
  f32x2 c201; c201.x = 0.4f * vaf.x; c201.y = 0.4f * vaf.y;
  f32x2 c223; c223.x = 0.4f * vaf.z; c223.y = 0.4f * vaf.w;
  const int k0 = offs[d], k1 = offs[d + 1];
  // dual online-softmax state (A: even batches, B: odd batches)
  float mA = -1e30f, dnA = 0.f, mB = -1e30f, dnB = 0.f;
  f32x2 aA01 = {0.f, 0.f}, aA23 = {0.f, 0.f};
  f32x2 aB01 = {0.f, 0.f}, aB23 = {0.f, 0.f};
  for (int kb = k0; kb < k1; kb += 64) {
    const int nk = min(64, k1 - kb);
    int2 ce = make_int2(0, 0);
    if (lane < nk) ce = csr[kb + lane];
    uint2 cur[4];
    float eac[4];
#pragma unroll
    for (int i = 0; i < 4; ++i) {
      int s = __shfl(ce.x, i);
      eac[i] = __int_as_float(__shfl(ce.y, i));
      cur[i] = *reinterpret_cast<const uint2*>(xc + (size_t)s * 512 + c4);
    }
    for (int j = 0; j < nk; j += 4) {
      float p[4];
      f32x2 x01s[4], x23s[4];
#pragma unroll
      for (int i = 0; i < 4; ++i) {
        f32x2 x01 = bfpair(cur[i].x), x23 = bfpair(cur[i].y);
        f32x2 eav = vbc2(eac[i]);
        f32x2 m01 = x01 + vfma2(eav, ve01, xr01);
        f32x2 m23 = x23 + vfma2(eav, ve23, xr23);
        f32x2 t = m01 * c101;
        t = vfma2(vabs2(m01), c201, t);
        t = vfma2(m23, c123, t);
        t = vfma2(vabs2(m23), c223, t);
        p[i] = (j + i < nk) ? (t.x + t.y) : -1e30f;
        x01s[i] = x01; x23s[i] = x23;
      }
      if (j + 4 < nk) {
#pragma unroll
        for (int i = 0; i < 4; ++i) {
          int s = __shfl(ce.x, j + 4 + i);
          eac[i] = __int_as_float(__shfl(ce.y, j + 4 + i));
          cur[i] = *reinterpret_cast<const uint2*>(xc + (size_t)s * 512 + c4);
        }
      }
      // 4 interleaved 32-lane reductions: 4 DPP stages (VALU) + 1 shuffle
#pragma unroll
      for (int i = 0; i < 4; ++i) p[i] = dpp_add<DPP_XOR1>(p[i]);
#pragma unroll
      for (int i = 0; i < 4; ++i) p[i] = dpp_add<DPP_XOR2>(p[i]);
#pragma unroll
      for (int i = 0; i < 4; ++i) p[i] = dpp_add<DPP_HM>(p[i]);
#pragma unroll
      for (int i = 0; i < 4; ++i) p[i] = dpp_add<DPP_M>(p[i]);
#pragma unroll
      for (int i = 0; i < 4; ++i) p[i] += __shfl_xor(p[i], 16, 64);
      float pmax = fmaxf(fmaxf(p[0], p[1]), fmaxf(p[2], p[3]));
#define UPDATE1(MM, DN, A01, A23)                                            \
      {                                                                      \
        float nm = fmaxf(MM, pmax);                                          \
        float corr = __expf(MM - nm);                                        \
        float w0 = __expf(p[0] - nm), w1 = __expf(p[1] - nm);                \
        float w2 = __expf(p[2] - nm), w3 = __expf(p[3] - nm);                \
        MM = nm;                                                             \
        DN = fmaf(DN, corr, (w0 + w1) + (w2 + w3));                          \
        f32x2 corrv = vbc2(corr);                                            \
        f32x2 t0 = vbc2(w0) * x01s[0];                                       \
        t0 = vfma2(vbc2(w1), x01s[1], t0);                                   \
        t0 = vfma2(vbc2(w2), x01s[2], t0);                                   \
        t0 = vfma2(vbc2(w3), x01s[3], t0);                                   \
        A01 = vfma2(A01, corrv, t0);                                         \
        f32x2 t1 = vbc2(w0) * x23s[0];                                       \
        t1 = vfma2(vbc2(w1), x23s[1], t1);                                   \
        t1 = vfma2(vbc2(w2), x23s[2], t1);                                   \
        t1 = vfma2(vbc2(w3), x23s[3], t1);                                   \
        A23 = vfma2(A23, corrv, t1);                                         \
      }
      if (j & 4) UPDATE1(mB, dnB, aB01, aB23)
      else       UPDATE1(mA, dnA, aA01, aA23)
#undef UPDATE1
    }
  }
  // merge dual states
  float M = fmaxf(mA, mB);
  float cA = __expf(mA - M), cB = __expf(mB - M);
  float den = fmaf(dnA, cA, dnB * cB);
  f32x2 a01 = vfma2(aA01, vbc2(cA), aB01 * vbc2(cB));
  f32x2 a23 = vfma2(aA23, vbc2(cA), aB23 * vbc2(cB));
  float rden = 1.f / den;
  float4 b = *reinterpret_cast<const float4*>(bias + c4);
  float r0 = fmaf(a01.x, rden, b.x); r0 = r0 > 0.f ? r0 : expm1f(r0);
  float r1 = fmaf(a01.y, rden, b.y); r1 = r1 > 0.f ? r1 : expm1f(r1);
  float r2 = fmaf(a23.x, rden, b.z); r2 = r2 > 0.f ? r2 : expm1f(r2);
  float r3 = fmaf(a23.y, rden, b.w); r3 = r3 > 0.f ? r3 : expm1f(r3);
  ushort4 o;
  o.x = f2bf(r0); o.y = f2bf(r1); o.z = f2bf(r2); o.w = f2bf(r3);
  *reinterpret_cast<ushort4*>(hout + (size_t)d * HC1 + c4) = o;
}

// ---------- fused layer 2: wave/node, 1 ch/lane, 4-edge batch, DPP, dual state ----------
__global__ __launch_bounds__(256) void fused2_kernel(
    const int* __restrict__ offs, const int2* __restrict__ csr,
    const unsigned short* __restrict__ xc2, const float* __restrict__ We,
    const float* __restrict__ att, const float* __restrict__ bias,
    float* __restrict__ out) {
  const int wid = threadIdx.x >> 6, lane = threadIdx.x & 63;
  const int d = blockIdx.x * 4 + wid;
  if (d >= N_NODES) return;
  float xr = bf2f(xc2[(size_t)d * 128 + 64 + lane]);
  float ve = We[lane];
  float va = att[lane];
  float cc1 = 0.6f * va, cc2 = 0.4f * va;
  const int k0 = offs[d], k1 = offs[d + 1];
  float mA = -1e30f, dnA = 0.f, accA = 0.f;
  float mB = -1e30f, dnB = 0.f, accB = 0.f;
  for (int kb = k0; kb < k1; kb += 64) {
    const int nk = min(64, k1 - kb);
    int2 ce = make_int2(0, 0);
    if (lane < nk) ce = csr[kb + lane];
    float curx[4], eac[4];
#pragma unroll
    for (int i = 0; i < 4; ++i) {
      int s = __shfl(ce.x, i);
      eac[i] = __int_as_float(__shfl(ce.y, i));
      curx[i] = bf2f(xc2[(size_t)s * 128 + lane]);
    }
    for (int j = 0; j < nk; j += 4) {
      float p[4], xs[4];
#pragma unroll
      for (int i = 0; i < 4; ++i) {
        float x = curx[i];
        float m = x + fmaf(eac[i], ve, xr);
        float pp = fmaf(cc2, fabsf(m), cc1 * m);
        p[i] = (j + i < nk) ? pp : -1e30f;
        xs[i] = x;
      }
      if (j + 4 < nk) {
#pragma unroll
        for (int i = 0; i < 4; ++i) {
          int s = __shfl(ce.x, j + 4 + i);
          eac[i] = __int_as_float(__shfl(ce.y, j + 4 + i));
          curx[i] = bf2f(xc2[(size_t)s * 128 + lane]);
        }
      }
      // 64-lane reductions: 4 DPP stages + 2 shuffles
#pragma unroll
      for (int i = 0; i < 4; ++i) p[i] = dpp_add<DPP_XOR1>(p[i]);
#pragma unroll
      for (int i = 0; i < 4; ++i) p[i] = dpp_add<DPP_XOR2>(p[i]);
#pragma unroll
      for (int i = 0; i < 4; ++i) p[i] = dpp_add<DPP_HM>(p[i]);
#pragma unroll
      for (int i = 0; i < 4; ++i) p[i] = dpp_add<DPP_M>(p[i]);
#pragma unroll
      for (int i = 0; i < 4; ++i) p[i] += __shfl_xor(p[i], 16, 64);
#pragma unroll
      for (int i = 0; i < 4; ++i) p[i] += __shfl_xor(p[i], 32, 64);
      float pmax = fmaxf(fmaxf(p[0], p[1]), fmaxf(p[2], p[3]));
#define UPDATE2(MM, DN, AC)                                                  \
      {                                                                      \
        float nm = fmaxf(MM, pmax);                                          \
        float corr = __expf(MM - nm);                                        \
        float w0 = __expf(p[0] - nm), w1 = __expf(p[1] - nm);                \
        float w2 = __expf(p[2] - nm), w3 = __expf(p[3] - nm);                \
        MM = nm;                                                             \
        DN = fmaf(DN, corr, (w0 + w1) + (w2 + w3));                          \
        float t = fmaf(w0, xs[0], fmaf(w1, xs[1], fmaf(w2, xs[2], w3 * xs[3])));\
        AC = fmaf(AC, corr, t);                                              \
      }
      if (j & 4) UPDATE2(mB, dnB, accB)
      else       UPDATE2(mA, dnA, accA)
#undef UPDATE2
    }
  }
  float M = fmaxf(mA, mB);
  float cA = __expf(mA - M), cB = __expf(mB - M);
  float den = fmaf(dnA, cA, dnB * cB);
  float acc = fmaf(accA, cA, accB * cB);
  out[(size_t)d * OUT_DIM + lane] = acc / den + bias[lane];
}

extern "C" void kernel_launch(void* const* d_in, const int* in_sizes, int n_in,
                              void* d_out, int out_size, void* d_ws, size_t ws_size,
                              hipStream_t stream) {
  const float* x     = (const float*)d_in[0];
  const int*   ei    = (const int*)d_in[1];
  const float* eattr = (const float*)d_in[2];
  const float* W1l   = (const float*)d_in[3];
  const float* b1l   = (const float*)d_in[4];
  const float* W1r   = (const float*)d_in[5];
  const float* b1r   = (const float*)d_in[6];
  const float* W1e   = (const float*)d_in[7];
  const float* att1  = (const float*)d_in[8];
  const float* bias1 = (const float*)d_in[9];
  const float* W2l   = (const float*)d_in[10];
  const float* b2l   = (const float*)d_in[11];
  const float* W2r   = (const float*)d_in[12];
  const float* b2r   = (const float*)d_in[13];
  const float* W2e   = (const float*)d_in[14];
  const float* att2  = (const float*)d_in[15];
  const float* bias2 = (const float*)d_in[16];
  const int* src = ei;
  const int* dst = ei + E_EDGES;
  float* out = (float*)d_out;

  // workspace layout (bytes; all chunks 8B-aligned)
  char* w = (char*)d_ws;
  unsigned short* xb  = (unsigned short*)w;  w += (size_t)N_NODES * IN_DIM * 2;  // [N][512] bf16
  unsigned short* W1T = (unsigned short*)w;  w += (size_t)IN_DIM * 512 * 2;      // [512][512]
  unsigned short* W2T = (unsigned short*)w;  w += (size_t)128 * HC1 * 2;         // [128][256]
  unsigned short* xc1 = (unsigned short*)w;  w += (size_t)N_NODES * 512 * 2;     // [N][512] xl|xr
  unsigned short* h   = (unsigned short*)w;  w += (size_t)N_NODES * HC1 * 2;     // [N][256]
  unsigned short* xc2 = (unsigned short*)w;  w += (size_t)N_NODES * 128 * 2;     // [N][128] xl2|xr2
  float* bcat1  = (float*)w;                 w += 512 * 4;
  float* bcat2  = (float*)w;                 w += 128 * 4;
  unsigned long long* pk = (unsigned long long*)w;  w += (size_t)N_NODES * 8;
  int* offs     = (int*)w;                   w += (size_t)(N_NODES + 4) * 4;     // 8B-align pad
  int2* csr     = (int2*)w;                  w += (size_t)EN_TOT * 8;

  (void)hipMemsetAsync(pk, 0, (size_t)N_NODES * 8, stream);

  const int T = 256;
  // merged edge-stats + x->bf16 + weight prep (stats interleaved 1:8 with xconv)
  {
    int wprep_blocks = (512 * 512 + 128 * 256 + T - 1) / T;   // 1152
    prep_kernel<<<PREP_IL + wprep_blocks, T, 0, stream>>>(
        dst, eattr, pk, x, xb, W1l, W1r, b1l, b1r, W1T, bcat1,
        W2l, W2r, b2l, b2r, W2T, bcat2);
  }
  scan_kernel<<<1, 1024, 0, stream>>>(pk, offs);

  // merged CSR fill + layer-1 GEMM (128x128), interleaved even/odd
  csr_gemm1_kernel<<<2 * GEMM_BLOCKS + (CSR_BLOCKS - GEMM_BLOCKS), T, 0, stream>>>(
      src, dst, eattr, offs, pk, csr, xb, W1T, bcat1, xc1);

  fused1_kernel<<<(N_NODES + 3) / 4, T, 0, stream>>>(offs, csr, xc1, W1e, att1, bias1, h);

  // layer 2: GEMM [N,256]@[256,128] -> xc2 (BM=64, BN=64: 626 blocks)
  {
    dim3 grid((N_NODES + 63) / 64, 128 / 64);
    gemm_tile_kernel<64, 64><<<grid, T, 0, stream>>>(h, W2T, bcat2, xc2, N_NODES, HC1, 128);
  }
  fused2_kernel<<<(N_NODES + 3) / 4, T, 0, stream>>>(offs, csr, xc2, W2e, att2, bias2, out);
}

// Round 16
// 162.942 us; speedup vs baseline: 1.0084x; 1.0084x over previous
//
#include <hip/hip_runtime.h>

#define N_NODES 20000
#define E_EDGES 320000
#define EN_TOT  (E_EDGES + N_NODES)   // edges + self loops = 340000
#define IN_DIM  512
#define H1      2
#define C1      128
#define HC1     256                    // H1*C1
#define OUT_DIM 64

typedef __attribute__((ext_vector_type(8))) short short8;
typedef __attribute__((ext_vector_type(4))) float f32x4;
typedef __attribute__((ext_vector_type(2))) float f32x2;

__device__ __forceinline__ unsigned short f2bf(float f) {
  unsigned u = __float_as_uint(f);
  u += 0x7fffu + ((u >> 16) & 1u);    // RNE
  return (unsigned short)(u >> 16);
}
__device__ __forceinline__ float bf2f(unsigned short s) {
  return __uint_as_float(((unsigned)s) << 16);
}
__device__ __forceinline__ f32x2 bfpair(unsigned u) {
  f32x2 r;
  r.x = __uint_as_float(u << 16);
  r.y = __uint_as_float(u & 0xffff0000u);
  return r;
}
__device__ __forceinline__ f32x2 vabs2(f32x2 v) {
  f32x2 r;
  r.x = __uint_as_float(__float_as_uint(v.x) & 0x7fffffffu);
  r.y = __uint_as_float(__float_as_uint(v.y) & 0x7fffffffu);
  return r;
}
__device__ __forceinline__ f32x2 vfma2(f32x2 a, f32x2 b, f32x2 c) {
  return __builtin_elementwise_fma(a, b, c);
}
__device__ __forceinline__ f32x2 vbc2(float s) { f32x2 r; r.x = s; r.y = s; return r; }

// VALU-speed cross-lane add via DPP (within 16-lane rows). All 64 lanes active.
#define DPP_XOR1 0xB1    // quad_perm(1,0,3,2)
#define DPP_XOR2 0x4E    // quad_perm(2,3,0,1)
#define DPP_HM   0x141   // row_half_mirror (lane^7 within 8)
#define DPP_M    0x140   // row_mirror (lane^15 within 16)
template<int CTRL>
__device__ __forceinline__ float dpp_add(float v) {
  return v + __int_as_float(__builtin_amdgcn_update_dpp(
      0, __float_as_int(v), CTRL, 0xF, 0xF, true));
}

// async global->LDS, 16B per lane; LDS dest = wave-uniform base + lane*16 (linear)
__device__ __forceinline__ void gl_lds16(const void* g, void* l) {
  __builtin_amdgcn_global_load_lds((const __attribute__((address_space(1))) void*)g,
                                   (__attribute__((address_space(3))) void*)l, 16, 0, 0);
}

// ---------- zero pk (replaces pathologically slow rocclr fillBuffer: 41.8us -> ~2us) ----------
__global__ void zero_pk_kernel(unsigned long long* __restrict__ pk) {
  int i = blockIdx.x * 256 + threadIdx.x;
  if (i < N_NODES) pk[i] = 0ull;
}

// ---------- merged prep: stats interleaved among xconv (1:8), then wprep ----------
#define STATS_BLOCKS 1250           // 320000 edges / 256
#define XCONV_BLOCKS 10000          // 2,560,000 float4 / 256 threads
#define PREP_IL (STATS_BLOCKS * 9)  // 11250 interleaved blocks
__global__ void prep_kernel(const int* __restrict__ dst, const float* __restrict__ eattr,
                            unsigned long long* __restrict__ pk,
                            const float* __restrict__ x, unsigned short* __restrict__ xb,
                            const float* __restrict__ W1l, const float* __restrict__ W1r,
                            const float* __restrict__ b1l, const float* __restrict__ b1r,
                            unsigned short* __restrict__ W1T, float* __restrict__ bcat1,
                            const float* __restrict__ W2l, const float* __restrict__ W2r,
                            const float* __restrict__ b2l, const float* __restrict__ b2r,
                            unsigned short* __restrict__ W2T, float* __restrict__ bcat2) {
  int bid = blockIdx.x;
  if (bid < PREP_IL) {
    int phase = bid % 9;
    if (phase == 8) {
      int e = (bid / 9) * 256 + threadIdx.x;
      if (e < E_EDGES) {
        int dd = dst[e];
        unsigned long long v = (1ull << 40) |
            (unsigned long long)(unsigned)(eattr[e] * 16777216.0f);
        atomicAdd(&pk[dd], v);
      }
    } else {
      int i = ((bid / 9) * 8 + phase) * 256 + threadIdx.x;   // < 2,560,000 float4s
      float4 v = *reinterpret_cast<const float4*>(x + (size_t)i * 4);
      ushort4 o;
      o.x = f2bf(v.x); o.y = f2bf(v.y); o.z = f2bf(v.z); o.w = f2bf(v.w);
      *reinterpret_cast<ushort4*>(xb + (size_t)i * 4) = o;
    }
  } else {
    int idx = (bid - PREP_IL) * 256 + threadIdx.x;
    const int B1 = 512 * 512;
    if (idx < B1) {
      int n = idx >> 9, k = idx & 511;
      const float* W = (n < 256) ? W1l : W1r;
      int nn = n & 255;
      W1T[idx] = f2bf(W[(size_t)k * 256 + nn]);
      if (k == 0) bcat1[n] = (n < 256) ? b1l[nn] : b1r[nn];
    } else if (idx < B1 + 128 * 256) {
      int t = idx - B1;
      int n = t >> 8, k = t & 255;
      const float* W = (n < 64) ? W2l : W2r;
      int nn = n & 63;
      W2T[t] = f2bf(W[(size_t)k * 64 + nn]);
      if (k == 0) bcat2[n] = (n < 64) ? b2l[nn] : b2r[nn];
    }
  }
}

// ---------- exclusive scan over row lengths (deg+1), single block ----------
__global__ void scan_kernel(const unsigned long long* __restrict__ pk, int* __restrict__ offs) {
  __shared__ int psum[1024];
  const int T = 1024;
  int tid = threadIdx.x;
  const int per = (N_NODES + T - 1) / T;
  int base = tid * per;
  int s = 0;
  for (int i = 0; i < per; ++i) {
    int n = base + i;
    if (n < N_NODES) s += (int)(pk[n] >> 40) + 1;
  }
  psum[tid] = s;
  __syncthreads();
  for (int off = 1; off < T; off <<= 1) {
    int v = (tid >= off) ? psum[tid - off] : 0;
    __syncthreads();
    psum[tid] += v;
    __syncthreads();
  }
  int run = (tid > 0) ? psum[tid - 1] : 0;
  for (int i = 0; i < per; ++i) {
    int n = base + i;
    if (n < N_NODES) {
      offs[n] = run;
      run += (int)(pk[n] >> 40) + 1;
    }
  }
  if (tid == T - 1) offs[N_NODES] = run;
}

// ---------- merged CSR fill + layer-1 GEMM (128x128), interleaved; global_load_lds ----------
// LDS layout: [m][kbs] linear; slot (m,kbs) holds global chunk kb = kbs ^ (m&7).
#define CSR_BLOCKS  1329   // ceil(340000/256)
#define GEMM_BLOCKS 628    // 157 * 4
__global__ __launch_bounds__(256) void csr_gemm1_kernel(
    const int* __restrict__ src, const int* __restrict__ dst, const float* __restrict__ eattr,
    const int* __restrict__ offs, unsigned long long* __restrict__ pk,
    int2* __restrict__ csr,
    const unsigned short* __restrict__ A,    // xb [M][512] bf16
    const unsigned short* __restrict__ BT,   // W1T [512][512] bf16
    const float* __restrict__ bias, unsigned short* __restrict__ C) {
  constexpr int BK = 64;
  __shared__ short8 AsV[128 * 8];   // 16 KB
  __shared__ short8 BsV[128 * 8];   // 16 KB
  const int bid = blockIdx.x;
  bool is_gemm;
  int sub;
  if (bid < 2 * GEMM_BLOCKS) { is_gemm = !(bid & 1); sub = bid >> 1; }
  else                       { is_gemm = false; sub = GEMM_BLOCKS + (bid - 2 * GEMM_BLOCKS); }
  if (!is_gemm) {
    int t = sub * 256 + threadIdx.x;
    if (t < N_NODES) {
      unsigned long long v = pk[t];   // low 40 bits (asum) never touched by decrements
      float sum = (float)(v & 0xFFFFFFFFFFull) * (1.0f / 16777216.0f);
      int deg = offs[t + 1] - offs[t] - 1;
      float la = sum / fmaxf((float)deg, 1.0f);
      csr[offs[t]] = make_int2(t, __float_as_int(la));
    } else if (t < N_NODES + E_EDGES) {
      int e = t - N_NODES;
      int dd = dst[e];
      unsigned long long old = atomicAdd(&pk[dd], (unsigned long long)(-(1ll << 40)));
      int p = offs[dd] + (int)(old >> 40);   // deg, deg-1, ..., 1
      csr[p] = make_int2(src[e], __float_as_int(eattr[e]));
    }
    return;
  }
  // ---- gemm part: M=N_NODES, K=512, N=512, BM=128, BN=128 ----
  const int g = sub;
  const int bm = (g >> 2) * 128;
  const int bn = (g & 3) * 128;
  constexpr int K = 512, N = 512, M = N_NODES;
  const int tid = threadIdx.x;
  const int lane = tid & 63;
  const int wave = tid >> 6;
  const int wr = wave >> 1, wc = wave & 1;
  const int lrow = lane & 15, lk = lane >> 4;

  f32x4 acc[4][4] = {};

  for (int k0 = 0; k0 < K; k0 += BK) {
#pragma unroll
    for (int i = 0; i < 4; ++i) {
      int c = tid + i * 256;
      int m = c >> 3, kbs = c & 7;
      int kb = kbs ^ (m & 7);
      int gr = bm + m;
      if (gr < M)
        gl_lds16(A + (size_t)gr * K + k0 + kb * 8, &AsV[c]);
    }
#pragma unroll
    for (int i = 0; i < 4; ++i) {
      int c = tid + i * 256;
      int n = c >> 3, kbs = c & 7;
      int kb = kbs ^ (n & 7);
      gl_lds16(BT + (size_t)(bn + n) * K + k0 + kb * 8, &BsV[c]);
    }
    __syncthreads();
#pragma unroll
    for (int ks = 0; ks < 2; ++ks) {
      int kb = ks * 4 + lk;
      short8 a[4], b[4];
#pragma unroll
      for (int mf = 0; mf < 4; ++mf) {
        int r = wr * 64 + mf * 16 + lrow;
        a[mf] = AsV[r * 8 + (kb ^ (r & 7))];
      }
#pragma unroll
      for (int nf = 0; nf < 4; ++nf) {
        int n = wc * 64 + nf * 16 + lrow;
        b[nf] = BsV[n * 8 + (kb ^ (n & 7))];
      }
#pragma unroll
      for (int mf = 0; mf < 4; ++mf)
#pragma unroll
        for (int nf = 0; nf < 4; ++nf)
          acc[mf][nf] = __builtin_amdgcn_mfma_f32_16x16x32_bf16(a[mf], b[nf], acc[mf][nf], 0, 0, 0);
    }
    __syncthreads();
  }
#pragma unroll
  for (int mf = 0; mf < 4; ++mf) {
#pragma unroll
    for (int r = 0; r < 4; ++r) {
      int row = bm + wr * 64 + mf * 16 + (lane >> 4) * 4 + r;
      if (row >= M) continue;
#pragma unroll
      for (int nf = 0; nf < 4; ++nf) {
        int col = bn + wc * 64 + nf * 16 + (lane & 15);
        C[(size_t)row * N + col] = f2bf(acc[mf][nf][r] + bias[col]);
      }
    }
  }
}

// ---------- templated bf16 MFMA GEMM (layer 2), global_load_lds staging ----------
template<int BM, int BN>
__global__ __launch_bounds__(256) void gemm_tile_kernel(
    const unsigned short* __restrict__ A,   // [M][K] bf16
    const unsigned short* __restrict__ BT,  // [N][K] bf16
    const float* __restrict__ bias, unsigned short* __restrict__ C,
    int M, int K, int N) {
  constexpr int BK = 64;
  constexpr int MF = BM / 32;
  constexpr int NF = BN / 32;
  __shared__ short8 AsV[BM * 8];
  __shared__ short8 BsV[BN * 8];
  const int bm = blockIdx.x * BM;
  const int bn = blockIdx.y * BN;
  const int tid = threadIdx.x;
  const int lane = tid & 63;
  const int wave = tid >> 6;
  const int wr = wave >> 1, wc = wave & 1;
  const int lrow = lane & 15, lk = lane >> 4;

  f32x4 acc[MF][NF] = {};

  for (int k0 = 0; k0 < K; k0 += BK) {
#pragma unroll
    for (int i = 0; i < BM / 32; ++i) {
      int c = tid + i * 256;
      int m = c >> 3, kbs = c & 7;
      int kb = kbs ^ (m & 7);
      int gr = bm + m;
      if (gr < M)
        gl_lds16(A + (size_t)gr * K + k0 + kb * 8, &AsV[c]);
    }
#pragma unroll
    for (int i = 0; i < BN / 32; ++i) {
      int c = tid + i * 256;
      int n = c >> 3, kbs = c & 7;
      int kb = kbs ^ (n & 7);
      gl_lds16(BT + (size_t)(bn + n) * K + k0 + kb * 8, &BsV[c]);
    }
    __syncthreads();
#pragma unroll
    for (int ks = 0; ks < 2; ++ks) {
      int kb = ks * 4 + lk;
      short8 a[MF], b[NF];
#pragma unroll
      for (int mf = 0; mf < MF; ++mf) {
        int r = wr * (BM / 2) + mf * 16 + lrow;
        a[mf] = AsV[r * 8 + (kb ^ (r & 7))];
      }
#pragma unroll
      for (int nf = 0; nf < NF; ++nf) {
        int n = wc * (BN / 2) + nf * 16 + lrow;
        b[nf] = BsV[n * 8 + (kb ^ (n & 7))];
      }
#pragma unroll
      for (int mf = 0; mf < MF; ++mf)
#pragma unroll
        for (int nf = 0; nf < NF; ++nf)
          acc[mf][nf] = __builtin_amdgcn_mfma_f32_16x16x32_bf16(a[mf], b[nf], acc[mf][nf], 0, 0, 0);
    }
    __syncthreads();
  }
#pragma unroll
  for (int mf = 0; mf < MF; ++mf) {
#pragma unroll
    for (int r = 0; r < 4; ++r) {
      int row = bm + wr * (BM / 2) + mf * 16 + (lane >> 4) * 4 + r;
      if (row >= M) continue;
#pragma unroll
      for (int nf = 0; nf < NF; ++nf) {
        int col = bn + wc * (BN / 2) + nf * 16 + (lane & 15);
        C[(size_t)row * N + col] = f2bf(acc[mf][nf][r] + bias[col]);
      }
    }
  }
}

// ---------- fused layer 1: wave/node, 4-edge batch, prefetch, DPP reductions ----------
// xc row: [xl(256) | xr(256)]; lanes 0-31 = head0, 32-63 = head1; 4 ch/lane
__global__ __launch_bounds__(256) void fused1_kernel(
    const int* __restrict__ offs, const int2* __restrict__ csr,
    const unsigned short* __restrict__ xc, const float* __restrict__ We,
    const float* __restrict__ att, const float* __restrict__ bias,
    unsigned short* __restrict__ hout) {
  const int wid = threadIdx.x >> 6, lane = threadIdx.x & 63;
  const int d = blockIdx.x * 4 + wid;
  if (d >= N_NODES) return;
  const int c4 = lane * 4;
  uint2 urr = *reinterpret_cast<const uint2*>(xc + (size_t)d * 512 + 256 + c4);
  const f32x2 xr01 = bfpair(urr.x), xr23 = bfpair(urr.y);
  float4 vef = *reinterpret_cast<const float4*>(We + c4);
  float4 vaf = *reinterpret_cast<const float4*>(att + c4);
  f32x2 ve01; ve01.x = vef.x; ve01.y = vef.y;
  f32x2 ve23; ve23.x = vef.z; ve23.y = vef.w;
  f32x2 c101; c101.x = 0.6f * vaf.x; c101.y = 0.6f * vaf.y;
  f32x2 c123; c123.x = 0.6f * vaf.z; c123.y = 0.6f * vaf.w;
  f32x2 c201; c201.x = 0.4f * vaf.x; c201.y = 0.4f * vaf.y;
  f32x2 c223; c223.x = 0.4f * vaf.z; c223.y = 0.4f * vaf.w;
  const int k0 = offs[d], k1 = offs[d + 1];
  float mmax = -1e30f, den = 0.f;
  f32x2 a01 = {0.f, 0.f}, a23 = {0.f, 0.f};
  for (int kb = k0; kb < k1; kb += 64) {
    const int nk = min(64, k1 - kb);
    int2 ce = make_int2(0, 0);
    if (lane < nk) ce = csr[kb + lane];
    uint2 cur[4];
    float eac[4];
#pragma unroll
    for (int i = 0; i < 4; ++i) {
      int s = __shfl(ce.x, i);
      eac[i] = __int_as_float(__shfl(ce.y, i));
      cur[i] = *reinterpret_cast<const uint2*>(xc + (size_t)s * 512 + c4);
    }
    for (int j = 0; j < nk; j += 4) {
      float p[4];
      f32x2 x01s[4], x23s[4];
#pragma unroll
      for (int i = 0; i < 4; ++i) {
        f32x2 x01 = bfpair(cur[i].x), x23 = bfpair(cur[i].y);
        f32x2 eav = vbc2(eac[i]);
        f32x2 m01 = x01 + vfma2(eav, ve01, xr01);
        f32x2 m23 = x23 + vfma2(eav, ve23, xr23);
        f32x2 t = m01 * c101;
        t = vfma2(vabs2(m01), c201, t);
        t = vfma2(m23, c123, t);
        t = vfma2(vabs2(m23), c223, t);
        p[i] = (j + i < nk) ? (t.x + t.y) : -1e30f;
        x01s[i] = x01; x23s[i] = x23;
      }
      if (j + 4 < nk) {
#pragma unroll
        for (int i = 0; i < 4; ++i) {
          int s = __shfl(ce.x, j + 4 + i);
          eac[i] = __int_as_float(__shfl(ce.y, j + 4 + i));
          cur[i] = *reinterpret_cast<const uint2*>(xc + (size_t)s * 512 + c4);
        }
      }
      // 4 interleaved 32-lane reductions: 4 DPP stages (VALU) + 1 shuffle
#pragma unroll
      for (int i = 0; i < 4; ++i) p[i] = dpp_add<DPP_XOR1>(p[i]);
#pragma unroll
      for (int i = 0; i < 4; ++i) p[i] = dpp_add<DPP_XOR2>(p[i]);
#pragma unroll
      for (int i = 0; i < 4; ++i) p[i] = dpp_add<DPP_HM>(p[i]);
#pragma unroll
      for (int i = 0; i < 4; ++i) p[i] = dpp_add<DPP_M>(p[i]);
#pragma unroll
      for (int i = 0; i < 4; ++i) p[i] += __shfl_xor(p[i], 16, 64);
      float nm = fmaxf(mmax, fmaxf(fmaxf(p[0], p[1]), fmaxf(p[2], p[3])));
      float corr = __expf(mmax - nm);
      float w0 = __expf(p[0] - nm), w1 = __expf(p[1] - nm);
      float w2 = __expf(p[2] - nm), w3 = __expf(p[3] - nm);
      mmax = nm;
      den = fmaf(den, corr, (w0 + w1) + (w2 + w3));
      f32x2 corrv = vbc2(corr);
      f32x2 t0 = vbc2(w0) * x01s[0];
      t0 = vfma2(vbc2(w1), x01s[1], t0);
      t0 = vfma2(vbc2(w2), x01s[2], t0);
      t0 = vfma2(vbc2(w3), x01s[3], t0);
      a01 = vfma2(a01, corrv, t0);
      f32x2 t1 = vbc2(w0) * x23s[0];
      t1 = vfma2(vbc2(w1), x23s[1], t1);
      t1 = vfma2(vbc2(w2), x23s[2], t1);
      t1 = vfma2(vbc2(w3), x23s[3], t1);
      a23 = vfma2(a23, corrv, t1);
    }
  }
  float rden = 1.f / den;
  float4 b = *reinterpret_cast<const float4*>(bias + c4);
  float r0 = fmaf(a01.x, rden, b.x); r0 = r0 > 0.f ? r0 : expm1f(r0);
  float r1 = fmaf(a01.y, rden, b.y); r1 = r1 > 0.f ? r1 : expm1f(r1);
  float r2 = fmaf(a23.x, rden, b.z); r2 = r2 > 0.f ? r2 : expm1f(r2);
  float r3 = fmaf(a23.y, rden, b.w); r3 = r3 > 0.f ? r3 : expm1f(r3);
  ushort4 o;
  o.x = f2bf(r0); o.y = f2bf(r1); o.z = f2bf(r2); o.w = f2bf(r3);
  *reinterpret_cast<ushort4*>(hout + (size_t)d * HC1 + c4) = o;
}

// ---------- fused layer 2: wave/node, 1 ch/lane, 4-edge batch, DPP reductions ----------
__global__ __launch_bounds__(256) void fused2_kernel(
    const int* __restrict__ offs, const int2* __restrict__ csr,
    const unsigned short* __restrict__ xc2, const float* __restrict__ We,
    const float* __restrict__ att, const float* __restrict__ bias,
    float* __restrict__ out) {
  const int wid = threadIdx.x >> 6, lane = threadIdx.x & 63;
  const int d = blockIdx.x * 4 + wid;
  if (d >= N_NODES) return;
  float xr = bf2f(xc2[(size_t)d * 128 + 64 + lane]);
  float ve = We[lane];
  float va = att[lane];
  float cc1 = 0.6f * va, cc2 = 0.4f * va;
  const int k0 = offs[d], k1 = offs[d + 1];
  float mmax = -1e30f, den = 0.f, acc = 0.f;
  for (int kb = k0; kb < k1; kb += 64) {
    const int nk = min(64, k1 - kb);
    int2 ce = make_int2(0, 0);
    if (lane < nk) ce = csr[kb + lane];
    float curx[4], eac[4];
#pragma unroll
    for (int i = 0; i < 4; ++i) {
      int s = __shfl(ce.x, i);
      eac[i] = __int_as_float(__shfl(ce.y, i));
      curx[i] = bf2f(xc2[(size_t)s * 128 + lane]);
    }
    for (int j = 0; j < nk; j += 4) {
      float p[4], xs[4];
#pragma unroll
      for (int i = 0; i < 4; ++i) {
        float x = curx[i];
        float m = x + fmaf(eac[i], ve, xr);
        float pp = fmaf(cc2, fabsf(m), cc1 * m);
        p[i] = (j + i < nk) ? pp : -1e30f;
        xs[i] = x;
      }
      if (j + 4 < nk) {
#pragma unroll
        for (int i = 0; i < 4; ++i) {
          int s = __shfl(ce.x, j + 4 + i);
          eac[i] = __int_as_float(__shfl(ce.y, j + 4 + i));
          curx[i] = bf2f(xc2[(size_t)s * 128 + lane]);
        }
      }
      // 64-lane reductions: 4 DPP stages + 2 shuffles
#pragma unroll
      for (int i = 0; i < 4; ++i) p[i] = dpp_add<DPP_XOR1>(p[i]);
#pragma unroll
      for (int i = 0; i < 4; ++i) p[i] = dpp_add<DPP_XOR2>(p[i]);
#pragma unroll
      for (int i = 0; i < 4; ++i) p[i] = dpp_add<DPP_HM>(p[i]);
#pragma unroll
      for (int i = 0; i < 4; ++i) p[i] = dpp_add<DPP_M>(p[i]);
#pragma unroll
      for (int i = 0; i < 4; ++i) p[i] += __shfl_xor(p[i], 16, 64);
#pragma unroll
      for (int i = 0; i < 4; ++i) p[i] += __shfl_xor(p[i], 32, 64);
      float nm = fmaxf(mmax, fmaxf(fmaxf(p[0], p[1]), fmaxf(p[2], p[3])));
      float corr = __expf(mmax - nm);
      float w0 = __expf(p[0] - nm), w1 = __expf(p[1] - nm);
      float w2 = __expf(p[2] - nm), w3 = __expf(p[3] - nm);
      mmax = nm;
      den = fmaf(den, corr, (w0 + w1) + (w2 + w3));
      float t = fmaf(w0, xs[0], fmaf(w1, xs[1], fmaf(w2, xs[2], w3 * xs[3])));
      acc = fmaf(acc, corr, t);
    }
  }
  out[(size_t)d * OUT_DIM + lane] = acc / den + bias[lane];
}

extern "C" void kernel_launch(void* const* d_in, const int* in_sizes, int n_in,
                              void* d_out, int out_size, void* d_ws, size_t ws_size,
                              hipStream_t stream) {
  const float* x     = (const float*)d_in[0];
  const int*   ei    = (const int*)d_in[1];
  const float* eattr = (const float*)d_in[2];
  const float* W1l   = (const float*)d_in[3];
  const float* b1l   = (const float*)d_in[4];
  const float* W1r   = (const float*)d_in[5];
  const float* b1r   = (const float*)d_in[6];
  const float* W1e   = (const float*)d_in[7];
  const float* att1  = (const float*)d_in[8];
  const float* bias1 = (const float*)d_in[9];
  const float* W2l   = (const float*)d_in[10];
  const float* b2l   = (const float*)d_in[11];
  const float* W2r   = (const float*)d_in[12];
  const float* b2r   = (const float*)d_in[13];
  const float* W2e   = (const float*)d_in[14];
  const float* att2  = (const float*)d_in[15];
  const float* bias2 = (const float*)d_in[16];
  const int* src = ei;
  const int* dst = ei + E_EDGES;
  float* out = (float*)d_out;

  // workspace layout (bytes; all chunks 8B-aligned)
  char* w = (char*)d_ws;
  unsigned short* xb  = (unsigned short*)w;  w += (size_t)N_NODES * IN_DIM * 2;  // [N][512] bf16
  unsigned short* W1T = (unsigned short*)w;  w += (size_t)IN_DIM * 512 * 2;      // [512][512]
  unsigned short* W2T = (unsigned short*)w;  w += (size_t)128 * HC1 * 2;         // [128][256]
  unsigned short* xc1 = (unsigned short*)w;  w += (size_t)N_NODES * 512 * 2;     // [N][512] xl|xr
  unsigned short* h   = (unsigned short*)w;  w += (size_t)N_NODES * HC1 * 2;     // [N][256]
  unsigned short* xc2 = (unsigned short*)w;  w += (size_t)N_NODES * 128 * 2;     // [N][128] xl2|xr2
  float* bcat1  = (float*)w;                 w += 512 * 4;
  float* bcat2  = (float*)w;                 w += 128 * 4;
  unsigned long long* pk = (unsigned long long*)w;  w += (size_t)N_NODES * 8;
  int* offs     = (int*)w;                   w += (size_t)(N_NODES + 4) * 4;     // 8B-align pad
  int2* csr     = (int2*)w;                  w += (size_t)EN_TOT * 8;

  const int T = 256;
  // zero pk with our own kernel (rocclr fillBuffer measured at 41.8us for 160KB!)
  zero_pk_kernel<<<(N_NODES + T - 1) / T, T, 0, stream>>>(pk);

  // merged edge-stats + x->bf16 + weight prep (stats interleaved 1:8 with xconv)
  {
    int wprep_blocks = (512 * 512 + 128 * 256 + T - 1) / T;   // 1152
    prep_kernel<<<PREP_IL + wprep_blocks, T, 0, stream>>>(
        dst, eattr, pk, x, xb, W1l, W1r, b1l, b1r, W1T, bcat1,
        W2l, W2r, b2l, b2r, W2T, bcat2);
  }
  scan_kernel<<<1, 1024, 0, stream>>>(pk, offs);

  // merged CSR fill + layer-1 GEMM (128x128), interleaved even/odd
  csr_gemm1_kernel<<<2 * GEMM_BLOCKS + (CSR_BLOCKS - GEMM_BLOCKS), T, 0, stream>>>(
      src, dst, eattr, offs, pk, csr, xb, W1T, bcat1, xc1);

  fused1_kernel<<<(N_NODES + 3) / 4, T, 0, stream>>>(offs, csr, xc1, W1e, att1, bias1, h);

  // layer 2: GEMM [N,256]@[256,128] -> xc2 (BM=64, BN=64: 626 blocks)
  {
    dim3 grid((N_NODES + 63) / 64, 128 / 64);
    gemm_tile_kernel<64, 64><<<grid, T, 0, stream>>>(h, W2T, bcat2, xc2, N_NODES, HC1, 128);
  }
  fused2_kernel<<<(N_NODES + 3) / 4, T, 0, stream>>>(offs, csr, xc2, W2e, att2, bias2, out);
}

// Round 17
// 162.897 us; speedup vs baseline: 1.0086x; 1.0003x over previous
//
#include <hip/hip_runtime.h>

#define N_NODES 20000
#define E_EDGES 320000
#define EN_TOT  (E_EDGES + N_NODES)   // edges + self loops = 340000
#define IN_DIM  512
#define H1      2
#define C1      128
#define HC1     256                    // H1*C1
#define OUT_DIM 64

typedef __attribute__((ext_vector_type(8))) short short8;
typedef __attribute__((ext_vector_type(4))) float f32x4;
typedef __attribute__((ext_vector_type(2))) float f32x2;

__device__ __forceinline__ unsigned short f2bf(float f) {
  unsigned u = __float_as_uint(f);
  u += 0x7fffu + ((u >> 16) & 1u);    // RNE
  return (unsigned short)(u >> 16);
}
__device__ __forceinline__ float bf2f(unsigned short s) {
  return __uint_as_float(((unsigned)s) << 16);
}
__device__ __forceinline__ f32x2 bfpair(unsigned u) {
  f32x2 r;
  r.x = __uint_as_float(u << 16);
  r.y = __uint_as_float(u & 0xffff0000u);
  return r;
}
__device__ __forceinline__ f32x2 vabs2(f32x2 v) {
  f32x2 r;
  r.x = __uint_as_float(__float_as_uint(v.x) & 0x7fffffffu);
  r.y = __uint_as_float(__float_as_uint(v.y) & 0x7fffffffu);
  return r;
}
__device__ __forceinline__ f32x2 vfma2(f32x2 a, f32x2 b, f32x2 c) {
  return __builtin_elementwise_fma(a, b, c);
}
__device__ __forceinline__ f32x2 vbc2(float s) { f32x2 r; r.x = s; r.y = s; return r; }

// VALU-speed cross-lane add via DPP (within 16-lane rows). All 64 lanes active.
#define DPP_XOR1 0xB1    // quad_perm(1,0,3,2)
#define DPP_XOR2 0x4E    // quad_perm(2,3,0,1)
#define DPP_HM   0x141   // row_half_mirror (lane^7 within 8)
#define DPP_M    0x140   // row_mirror (lane^15 within 16)
template<int CTRL>
__device__ __forceinline__ float dpp_add(float v) {
  return v + __int_as_float(__builtin_amdgcn_update_dpp(
      0, __float_as_int(v), CTRL, 0xF, 0xF, true));
}

// async global->LDS, 16B per lane; LDS dest = wave-uniform base + lane*16 (linear)
__device__ __forceinline__ void gl_lds16(const void* g, void* l) {
  __builtin_amdgcn_global_load_lds((const __attribute__((address_space(1))) void*)g,
                                   (__attribute__((address_space(3))) void*)l, 16, 0, 0);
}

// ---------- zero pk ----------
__global__ void zero_pk_kernel(unsigned long long* __restrict__ pk) {
  int i = blockIdx.x * 256 + threadIdx.x;
  if (i < N_NODES) pk[i] = 0ull;
}

// ---------- merged prep: stats interleaved among xconv (1:8), then wprep ----------
#define STATS_BLOCKS 1250           // 320000 edges / 256
#define XCONV_BLOCKS 10000          // 2,560,000 float4 / 256 threads
#define PREP_IL (STATS_BLOCKS * 9)  // 11250 interleaved blocks
__global__ void prep_kernel(const int* __restrict__ dst, const float* __restrict__ eattr,
                            unsigned long long* __restrict__ pk,
                            const float* __restrict__ x, unsigned short* __restrict__ xb,
                            const float* __restrict__ W1l, const float* __restrict__ W1r,
                            const float* __restrict__ b1l, const float* __restrict__ b1r,
                            unsigned short* __restrict__ W1T, float* __restrict__ bcat1,
                            const float* __restrict__ W2l, const float* __restrict__ W2r,
                            const float* __restrict__ b2l, const float* __restrict__ b2r,
                            unsigned short* __restrict__ W2T, float* __restrict__ bcat2) {
  int bid = blockIdx.x;
  if (bid < PREP_IL) {
    int phase = bid % 9;
    if (phase == 8) {
      int e = (bid / 9) * 256 + threadIdx.x;
      if (e < E_EDGES) {
        int dd = dst[e];
        unsigned long long v = (1ull << 40) |
            (unsigned long long)(unsigned)(eattr[e] * 16777216.0f);
        atomicAdd(&pk[dd], v);
      }
    } else {
      int i = ((bid / 9) * 8 + phase) * 256 + threadIdx.x;   // < 2,560,000 float4s
      float4 v = *reinterpret_cast<const float4*>(x + (size_t)i * 4);
      ushort4 o;
      o.x = f2bf(v.x); o.y = f2bf(v.y); o.z = f2bf(v.z); o.w = f2bf(v.w);
      *reinterpret_cast<ushort4*>(xb + (size_t)i * 4) = o;
    }
  } else {
    int idx = (bid - PREP_IL) * 256 + threadIdx.x;
    const int B1 = 512 * 512;
    if (idx < B1) {
      int n = idx >> 9, k = idx & 511;
      const float* W = (n < 256) ? W1l : W1r;
      int nn = n & 255;
      W1T[idx] = f2bf(W[(size_t)k * 256 + nn]);
      if (k == 0) bcat1[n] = (n < 256) ? b1l[nn] : b1r[nn];
    } else if (idx < B1 + 128 * 256) {
      int t = idx - B1;
      int n = t >> 8, k = t & 255;
      const float* W = (n < 64) ? W2l : W2r;
      int nn = n & 63;
      W2T[t] = f2bf(W[(size_t)k * 64 + nn]);
      if (k == 0) bcat2[n] = (n < 64) ? b2l[nn] : b2r[nn];
    }
  }
}

// ---------- exclusive scan over row lengths (deg+1), single block ----------
__global__ void scan_kernel(const unsigned long long* __restrict__ pk, int* __restrict__ offs) {
  __shared__ int psum[1024];
  const int T = 1024;
  int tid = threadIdx.x;
  const int per = (N_NODES + T - 1) / T;
  int base = tid * per;
  int s = 0;
  for (int i = 0; i < per; ++i) {
    int n = base + i;
    if (n < N_NODES) s += (int)(pk[n] >> 40) + 1;
  }
  psum[tid] = s;
  __syncthreads();
  for (int off = 1; off < T; off <<= 1) {
    int v = (tid >= off) ? psum[tid - off] : 0;
    __syncthreads();
    psum[tid] += v;
    __syncthreads();
  }
  int run = (tid > 0) ? psum[tid - 1] : 0;
  for (int i = 0; i < per; ++i) {
    int n = base + i;
    if (n < N_NODES) {
      offs[n] = run;
      run += (int)(pk[n] >> 40) + 1;
    }
  }
  if (tid == T - 1) offs[N_NODES] = run;
}

// ---------- merged CSR fill + layer-1 GEMM (128x128), interleaved; global_load_lds ----------
#define CSR_BLOCKS  1329   // ceil(340000/256)
#define GEMM_BLOCKS 628    // 157 * 4
__global__ __launch_bounds__(256) void csr_gemm1_kernel(
    const int* __restrict__ src, const int* __restrict__ dst, const float* __restrict__ eattr,
    const int* __restrict__ offs, unsigned long long* __restrict__ pk,
    int2* __restrict__ csr,
    const unsigned short* __restrict__ A,    // xb [M][512] bf16
    const unsigned short* __restrict__ BT,   // W1T [512][512] bf16
    const float* __restrict__ bias, unsigned short* __restrict__ C) {
  constexpr int BK = 64;
  __shared__ short8 AsV[128 * 8];   // 16 KB
  __shared__ short8 BsV[128 * 8];   // 16 KB
  const int bid = blockIdx.x;
  bool is_gemm;
  int sub;
  if (bid < 2 * GEMM_BLOCKS) { is_gemm = !(bid & 1); sub = bid >> 1; }
  else                       { is_gemm = false; sub = GEMM_BLOCKS + (bid - 2 * GEMM_BLOCKS); }
  if (!is_gemm) {
    int t = sub * 256 + threadIdx.x;
    if (t < N_NODES) {
      unsigned long long v = pk[t];   // low 40 bits (asum) never touched by decrements
      float sum = (float)(v & 0xFFFFFFFFFFull) * (1.0f / 16777216.0f);
      int deg = offs[t + 1] - offs[t] - 1;
      float la = sum / fmaxf((float)deg, 1.0f);
      csr[offs[t]] = make_int2(t, __float_as_int(la));
    } else if (t < N_NODES + E_EDGES) {
      int e = t - N_NODES;
      int dd = dst[e];
      unsigned long long old = atomicAdd(&pk[dd], (unsigned long long)(-(1ll << 40)));
      int p = offs[dd] + (int)(old >> 40);   // deg, deg-1, ..., 1
      csr[p] = make_int2(src[e], __float_as_int(eattr[e]));
    }
    return;
  }
  // ---- gemm part: M=N_NODES, K=512, N=512, BM=128, BN=128 ----
  const int g = sub;
  const int bm = (g >> 2) * 128;
  const int bn = (g & 3) * 128;
  constexpr int K = 512, N = 512, M = N_NODES;
  const int tid = threadIdx.x;
  const int lane = tid & 63;
  const int wave = tid >> 6;
  const int wr = wave >> 1, wc = wave & 1;
  const int lrow = lane & 15, lk = lane >> 4;

  f32x4 acc[4][4] = {};

  for (int k0 = 0; k0 < K; k0 += BK) {
#pragma unroll
    for (int i = 0; i < 4; ++i) {
      int c = tid + i * 256;
      int m = c >> 3, kbs = c & 7;
      int kb = kbs ^ (m & 7);
      int gr = bm + m;
      if (gr < M)
        gl_lds16(A + (size_t)gr * K + k0 + kb * 8, &AsV[c]);
    }
#pragma unroll
    for (int i = 0; i < 4; ++i) {
      int c = tid + i * 256;
      int n = c >> 3, kbs = c & 7;
      int kb = kbs ^ (n & 7);
      gl_lds16(BT + (size_t)(bn + n) * K + k0 + kb * 8, &BsV[c]);
    }
    __syncthreads();
#pragma unroll
    for (int ks = 0; ks < 2; ++ks) {
      int kb = ks * 4 + lk;
      short8 a[4], b[4];
#pragma unroll
      for (int mf = 0; mf < 4; ++mf) {
        int r = wr * 64 + mf * 16 + lrow;
        a[mf] = AsV[r * 8 + (kb ^ (r & 7))];
      }
#pragma unroll
      for (int nf = 0; nf < 4; ++nf) {
        int n = wc * 64 + nf * 16 + lrow;
        b[nf] = BsV[n * 8 + (kb ^ (n & 7))];
      }
#pragma unroll
      for (int mf = 0; mf < 4; ++mf)
#pragma unroll
        for (int nf = 0; nf < 4; ++nf)
          acc[mf][nf] = __builtin_amdgcn_mfma_f32_16x16x32_bf16(a[mf], b[nf], acc[mf][nf], 0, 0, 0);
    }
    __syncthreads();
  }
#pragma unroll
  for (int mf = 0; mf < 4; ++mf) {
#pragma unroll
    for (int r = 0; r < 4; ++r) {
      int row = bm + wr * 64 + mf * 16 + (lane >> 4) * 4 + r;
      if (row >= M) continue;
#pragma unroll
      for (int nf = 0; nf < 4; ++nf) {
        int col = bn + wc * 64 + nf * 16 + (lane & 15);
        C[(size_t)row * N + col] = f2bf(acc[mf][nf][r] + bias[col]);
      }
    }
  }
}

// ---------- templated bf16 MFMA GEMM (layer 2), global_load_lds staging ----------
template<int BM, int BN>
__global__ __launch_bounds__(256) void gemm_tile_kernel(
    const unsigned short* __restrict__ A,   // [M][K] bf16
    const unsigned short* __restrict__ BT,  // [N][K] bf16
    const float* __restrict__ bias, unsigned short* __restrict__ C,
    int M, int K, int N) {
  constexpr int BK = 64;
  constexpr int MF = BM / 32;
  constexpr int NF = BN / 32;
  __shared__ short8 AsV[BM * 8];
  __shared__ short8 BsV[BN * 8];
  const int bm = blockIdx.x * BM;
  const int bn = blockIdx.y * BN;
  const int tid = threadIdx.x;
  const int lane = tid & 63;
  const int wave = tid >> 6;
  const int wr = wave >> 1, wc = wave & 1;
  const int lrow = lane & 15, lk = lane >> 4;

  f32x4 acc[MF][NF] = {};

  for (int k0 = 0; k0 < K; k0 += BK) {
#pragma unroll
    for (int i = 0; i < BM / 32; ++i) {
      int c = tid + i * 256;
      int m = c >> 3, kbs = c & 7;
      int kb = kbs ^ (m & 7);
      int gr = bm + m;
      if (gr < M)
        gl_lds16(A + (size_t)gr * K + k0 + kb * 8, &AsV[c]);
    }
#pragma unroll
    for (int i = 0; i < BN / 32; ++i) {
      int c = tid + i * 256;
      int n = c >> 3, kbs = c & 7;
      int kb = kbs ^ (n & 7);
      gl_lds16(BT + (size_t)(bn + n) * K + k0 + kb * 8, &BsV[c]);
    }
    __syncthreads();
#pragma unroll
    for (int ks = 0; ks < 2; ++ks) {
      int kb = ks * 4 + lk;
      short8 a[MF], b[NF];
#pragma unroll
      for (int mf = 0; mf < MF; ++mf) {
        int r = wr * (BM / 2) + mf * 16 + lrow;
        a[mf] = AsV[r * 8 + (kb ^ (r & 7))];
      }
#pragma unroll
      for (int nf = 0; nf < NF; ++nf) {
        int n = wc * (BN / 2) + nf * 16 + lrow;
        b[nf] = BsV[n * 8 + (kb ^ (n & 7))];
      }
#pragma unroll
      for (int mf = 0; mf < MF; ++mf)
#pragma unroll
        for (int nf = 0; nf < NF; ++nf)
          acc[mf][nf] = __builtin_amdgcn_mfma_f32_16x16x32_bf16(a[mf], b[nf], acc[mf][nf], 0, 0, 0);
    }
    __syncthreads();
  }
#pragma unroll
  for (int mf = 0; mf < MF; ++mf) {
#pragma unroll
    for (int r = 0; r < 4; ++r) {
      int row = bm + wr * (BM / 2) + mf * 16 + (lane >> 4) * 4 + r;
      if (row >= M) continue;
#pragma unroll
      for (int nf = 0; nf < NF; ++nf) {
        int col = bn + wc * (BN / 2) + nf * 16 + (lane & 15);
        C[(size_t)row * N + col] = f2bf(acc[mf][nf][r] + bias[col]);
      }
    }
  }
}

// ---------- fused layer 1: wave/node, depth-2 pipelined 4-edge batches, DPP ----------
// xc row: [xl(256) | xr(256)]; lanes 0-31 = head0, 32-63 = head1; 4 ch/lane
__global__ __launch_bounds__(256) void fused1_kernel(
    const int* __restrict__ offs, const int2* __restrict__ csr,
    const unsigned short* __restrict__ xc, const float* __restrict__ We,
    const float* __restrict__ att, const float* __restrict__ bias,
    unsigned short* __restrict__ hout) {
  const int wid = threadIdx.x >> 6, lane = threadIdx.x & 63;
  const int d = blockIdx.x * 4 + wid;
  if (d >= N_NODES) return;
  const int c4 = lane * 4;
  uint2 urr = *reinterpret_cast<const uint2*>(xc + (size_t)d * 512 + 256 + c4);
  const f32x2 xr01 = bfpair(urr.x), xr23 = bfpair(urr.y);
  float4 vef = *reinterpret_cast<const float4*>(We + c4);
  float4 vaf = *reinterpret_cast<const float4*>(att + c4);
  f32x2 ve01; ve01.x = vef.x; ve01.y = vef.y;
  f32x2 ve23; ve23.x = vef.z; ve23.y = vef.w;
  f32x2 c101; c101.x = 0.6f * vaf.x; c101.y = 0.6f * vaf.y;
  f32x2 c123; c123.x = 0.6f * vaf.z; c123.y = 0.6f * vaf.w;
  f32x2 c201; c201.x = 0.4f * vaf.x; c201.y = 0.4f * vaf.y;
  f32x2 c223; c223.x = 0.4f * vaf.z; c223.y = 0.4f * vaf.w;
  const int k0 = offs[d], k1 = offs[d + 1];
  float mmax = -1e30f, den = 0.f;
  f32x2 a01 = {0.f, 0.f}, a23 = {0.f, 0.f};
  for (int kb = k0; kb < k1; kb += 64) {
    const int nk = min(64, k1 - kb);
    int2 ce = make_int2(0, 0);
    if (lane < nk) ce = csr[kb + lane];
    uint2 curA[4], curB[4];
    float eaA[4], eaB[4];
#pragma unroll
    for (int i = 0; i < 4; ++i) {
      int s = __shfl(ce.x, i);
      eaA[i] = __int_as_float(__shfl(ce.y, i));
      curA[i] = *reinterpret_cast<const uint2*>(xc + (size_t)s * 512 + c4);
    }
#pragma unroll
    for (int i = 0; i < 4; ++i) {
      int s = __shfl(ce.x, 4 + i);
      eaB[i] = __int_as_float(__shfl(ce.y, 4 + i));
      curB[i] = *reinterpret_cast<const uint2*>(xc + (size_t)s * 512 + c4);
    }
    for (int j = 0; j < nk; j += 8) {
#define SCORE1(CUR, EAC, JB)                                                  \
      {                                                                       \
        _Pragma("unroll")                                                     \
        for (int i = 0; i < 4; ++i) {                                         \
          f32x2 x01 = bfpair(CUR[i].x), x23 = bfpair(CUR[i].y);               \
          f32x2 eav = vbc2(EAC[i]);                                           \
          f32x2 m01 = x01 + vfma2(eav, ve01, xr01);                           \
          f32x2 m23 = x23 + vfma2(eav, ve23, xr23);                           \
          f32x2 t = m01 * c101;                                               \
          t = vfma2(vabs2(m01), c201, t);                                     \
          t = vfma2(m23, c123, t);                                            \
          t = vfma2(vabs2(m23), c223, t);                                     \
          p[i] = ((JB) + i < nk) ? (t.x + t.y) : -1e30f;                      \
          x01s[i] = x01; x23s[i] = x23;                                       \
        }                                                                     \
      }
#define RELOAD1(CUR, EAC, JB)                                                 \
      if ((JB) < nk) {                                                        \
        _Pragma("unroll")                                                     \
        for (int i = 0; i < 4; ++i) {                                         \
          int s = __shfl(ce.x, (JB) + i);                                     \
          EAC[i] = __int_as_float(__shfl(ce.y, (JB) + i));                    \
          CUR[i] = *reinterpret_cast<const uint2*>(xc + (size_t)s * 512 + c4);\
        }                                                                     \
      }
#define REDUCE_UPDATE1()                                                      \
      {                                                                       \
        _Pragma("unroll")                                                     \
        for (int i = 0; i < 4; ++i) p[i] = dpp_add<DPP_XOR1>(p[i]);           \
        _Pragma("unroll")                                                     \
        for (int i = 0; i < 4; ++i) p[i] = dpp_add<DPP_XOR2>(p[i]);           \
        _Pragma("unroll")                                                     \
        for (int i = 0; i < 4; ++i) p[i] = dpp_add<DPP_HM>(p[i]);             \
        _Pragma("unroll")                                                     \
        for (int i = 0; i < 4; ++i) p[i] = dpp_add<DPP_M>(p[i]);              \
        _Pragma("unroll")                                                     \
        for (int i = 0; i < 4; ++i) p[i] += __shfl_xor(p[i], 16, 64);         \
        float nm = fmaxf(mmax, fmaxf(fmaxf(p[0], p[1]), fmaxf(p[2], p[3]))); \
        float corr = __expf(mmax - nm);                                       \
        float w0 = __expf(p[0] - nm), w1 = __expf(p[1] - nm);                 \
        float w2 = __expf(p[2] - nm), w3 = __expf(p[3] - nm);                 \
        mmax = nm;                                                            \
        den = fmaf(den, corr, (w0 + w1) + (w2 + w3));                         \
        f32x2 corrv = vbc2(corr);                                             \
        f32x2 t0 = vbc2(w0) * x01s[0];                                        \
        t0 = vfma2(vbc2(w1), x01s[1], t0);                                    \
        t0 = vfma2(vbc2(w2), x01s[2], t0);                                    \
        t0 = vfma2(vbc2(w3), x01s[3], t0);                                    \
        a01 = vfma2(a01, corrv, t0);                                          \
        f32x2 t1 = vbc2(w0) * x23s[0];                                        \
        t1 = vfma2(vbc2(w1), x23s[1], t1);                                    \
        t1 = vfma2(vbc2(w2), x23s[2], t1);                                    \
        t1 = vfma2(vbc2(w3), x23s[3], t1);                                    \
        a23 = vfma2(a23, corrv, t1);                                          \
      }
      // batch A: edges j..j+3; reload A at j+8 before reduce
      {
        float p[4]; f32x2 x01s[4], x23s[4];
        SCORE1(curA, eaA, j)
        RELOAD1(curA, eaA, j + 8)
        REDUCE_UPDATE1()
      }
      // batch B: edges j+4..j+7; reload B at j+12
      if (j + 4 < nk) {
        float p[4]; f32x2 x01s[4], x23s[4];
        SCORE1(curB, eaB, j + 4)
        RELOAD1(curB, eaB, j + 12)
        REDUCE_UPDATE1()
      }
#undef SCORE1
#undef RELOAD1
#undef REDUCE_UPDATE1
    }
  }
  float rden = 1.f / den;
  float4 b = *reinterpret_cast<const float4*>(bias + c4);
  float r0 = fmaf(a01.x, rden, b.x); r0 = r0 > 0.f ? r0 : expm1f(r0);
  float r1 = fmaf(a01.y, rden, b.y); r1 = r1 > 0.f ? r1 : expm1f(r1);
  float r2 = fmaf(a23.x, rden, b.z); r2 = r2 > 0.f ? r2 : expm1f(r2);
  float r3 = fmaf(a23.y, rden, b.w); r3 = r3 > 0.f ? r3 : expm1f(r3);
  ushort4 o;
  o.x = f2bf(r0); o.y = f2bf(r1); o.z = f2bf(r2); o.w = f2bf(r3);
  *reinterpret_cast<ushort4*>(hout + (size_t)d * HC1 + c4) = o;
}

// ---------- fused layer 2: wave/node, depth-2 pipelined 4-edge batches, DPP ----------
__global__ __launch_bounds__(256) void fused2_kernel(
    const int* __restrict__ offs, const int2* __restrict__ csr,
    const unsigned short* __restrict__ xc2, const float* __restrict__ We,
    const float* __restrict__ att, const float* __restrict__ bias,
    float* __restrict__ out) {
  const int wid = threadIdx.x >> 6, lane = threadIdx.x & 63;
  const int d = blockIdx.x * 4 + wid;
  if (d >= N_NODES) return;
  float xr = bf2f(xc2[(size_t)d * 128 + 64 + lane]);
  float ve = We[lane];
  float va = att[lane];
  float cc1 = 0.6f * va, cc2 = 0.4f * va;
  const int k0 = offs[d], k1 = offs[d + 1];
  float mmax = -1e30f, den = 0.f, acc = 0.f;
  for (int kb = k0; kb < k1; kb += 64) {
    const int nk = min(64, k1 - kb);
    int2 ce = make_int2(0, 0);
    if (lane < nk) ce = csr[kb + lane];
    float curA[4], curB[4], eaA[4], eaB[4];
#pragma unroll
    for (int i = 0; i < 4; ++i) {
      int s = __shfl(ce.x, i);
      eaA[i] = __int_as_float(__shfl(ce.y, i));
      curA[i] = bf2f(xc2[(size_t)s * 128 + lane]);
    }
#pragma unroll
    for (int i = 0; i < 4; ++i) {
      int s = __shfl(ce.x, 4 + i);
      eaB[i] = __int_as_float(__shfl(ce.y, 4 + i));
      curB[i] = bf2f(xc2[(size_t)s * 128 + lane]);
    }
    for (int j = 0; j < nk; j += 8) {
#define SCORE2(CUR, EAC, JB)                                                  \
      {                                                                       \
        _Pragma("unroll")                                                     \
        for (int i = 0; i < 4; ++i) {                                         \
          float xx = CUR[i];                                                  \
          float m = xx + fmaf(EAC[i], ve, xr);                                \
          float pp = fmaf(cc2, fabsf(m), cc1 * m);                            \
          p[i] = ((JB) + i < nk) ? pp : -1e30f;                               \
          xs[i] = xx;                                                         \
        }                                                                     \
      }
#define RELOAD2(CUR, EAC, JB)                                                 \
      if ((JB) < nk) {                                                        \
        _Pragma("unroll")                                                     \
        for (int i = 0; i < 4; ++i) {                                         \
          int s = __shfl(ce.x, (JB) + i);                                     \
          EAC[i] = __int_as_float(__shfl(ce.y, (JB) + i));                    \
          CUR[i] = bf2f(xc2[(size_t)s * 128 + lane]);                         \
        }                                                                     \
      }
#define REDUCE_UPDATE2()                                                      \
      {                                                                       \
        _Pragma("unroll")                                                     \
        for (int i = 0; i < 4; ++i) p[i] = dpp_add<DPP_XOR1>(p[i]);           \
        _Pragma("unroll")                                                     \
        for (int i = 0; i < 4; ++i) p[i] = dpp_add<DPP_XOR2>(p[i]);           \
        _Pragma("unroll")                                                     \
        for (int i = 0; i < 4; ++i) p[i] = dpp_add<DPP_HM>(p[i]);             \
        _Pragma("unroll")                                                     \
        for (int i = 0; i < 4; ++i) p[i] = dpp_add<DPP_M>(p[i]);              \
        _Pragma("unroll")                                                     \
        for (int i = 0; i < 4; ++i) p[i] += __shfl_xor(p[i], 16, 64);         \
        _Pragma("unroll")                                                     \
        for (int i = 0; i < 4; ++i) p[i] += __shfl_xor(p[i], 32, 64);         \
        float nm = fmaxf(mmax, fmaxf(fmaxf(p[0], p[1]), fmaxf(p[2], p[3]))); \
        float corr = __expf(mmax - nm);                                       \
        float w0 = __expf(p[0] - nm), w1 = __expf(p[1] - nm);                 \
        float w2 = __expf(p[2] - nm), w3 = __expf(p[3] - nm);                 \
        mmax = nm;                                                            \
        den = fmaf(den, corr, (w0 + w1) + (w2 + w3));                         \
        float t = fmaf(w0, xs[0], fmaf(w1, xs[1], fmaf(w2, xs[2], w3 * xs[3])));\
        acc = fmaf(acc, corr, t);                                             \
      }
      {
        float p[4], xs[4];
        SCORE2(curA, eaA, j)
        RELOAD2(curA, eaA, j + 8)
        REDUCE_UPDATE2()
      }
      if (j + 4 < nk) {
        float p[4], xs[4];
        SCORE2(curB, eaB, j + 4)
        RELOAD2(curB, eaB, j + 12)
        REDUCE_UPDATE2()
      }
#undef SCORE2
#undef RELOAD2
#undef REDUCE_UPDATE2
    }
  }
  out[(size_t)d * OUT_DIM + lane] = acc / den + bias[lane];
}

extern "C" void kernel_launch(void* const* d_in, const int* in_sizes, int n_in,
                              void* d_out, int out_size, void* d_ws, size_t ws_size,
                              hipStream_t stream) {
  const float* x     = (const float*)d_in[0];
  const int*   ei    = (const int*)d_in[1];
  const float* eattr = (const float*)d_in[2];
  const float* W1l   = (const float*)d_in[3];
  const float* b1l   = (const float*)d_in[4];
  const float* W1r   = (const float*)d_in[5];
  const float* b1r   = (const float*)d_in[6];
  const float* W1e   = (const float*)d_in[7];
  const float* att1  = (const float*)d_in[8];
  const float* bias1 = (const float*)d_in[9];
  const float* W2l   = (const float*)d_in[10];
  const float* b2l   = (const float*)d_in[11];
  const float* W2r   = (const float*)d_in[12];
  const float* b2r   = (const float*)d_in[13];
  const float* W2e   = (const float*)d_in[14];
  const float* att2  = (const float*)d_in[15];
  const float* bias2 = (const float*)d_in[16];
  const int* src = ei;
  const int* dst = ei + E_EDGES;
  float* out = (float*)d_out;

  // workspace layout (bytes; all chunks 8B-aligned)
  char* w = (char*)d_ws;
  unsigned short* xb  = (unsigned short*)w;  w += (size_t)N_NODES * IN_DIM * 2;  // [N][512] bf16
  unsigned short* W1T = (unsigned short*)w;  w += (size_t)IN_DIM * 512 * 2;      // [512][512]
  unsigned short* W2T = (unsigned short*)w;  w += (size_t)128 * HC1 * 2;         // [128][256]
  unsigned short* xc1 = (unsigned short*)w;  w += (size_t)N_NODES * 512 * 2;     // [N][512] xl|xr
  unsigned short* h   = (unsigned short*)w;  w += (size_t)N_NODES * HC1 * 2;     // [N][256]
  unsigned short* xc2 = (unsigned short*)w;  w += (size_t)N_NODES * 128 * 2;     // [N][128] xl2|xr2
  float* bcat1  = (float*)w;                 w += 512 * 4;
  float* bcat2  = (float*)w;                 w += 128 * 4;
  unsigned long long* pk = (unsigned long long*)w;  w += (size_t)N_NODES * 8;
  int* offs     = (int*)w;                   w += (size_t)(N_NODES + 4) * 4;     // 8B-align pad
  int2* csr     = (int2*)w;                  w += (size_t)EN_TOT * 8;

  const int T = 256;
  zero_pk_kernel<<<(N_NODES + T - 1) / T, T, 0, stream>>>(pk);

  // merged edge-stats + x->bf16 + weight prep (stats interleaved 1:8 with xconv)
  {
    int wprep_blocks = (512 * 512 + 128 * 256 + T - 1) / T;   // 1152
    prep_kernel<<<PREP_IL + wprep_blocks, T, 0, stream>>>(
        dst, eattr, pk, x, xb, W1l, W1r, b1l, b1r, W1T, bcat1,
        W2l, W2r, b2l, b2r, W2T, bcat2);
  }
  scan_kernel<<<1, 1024, 0, stream>>>(pk, offs);

  // merged CSR fill + layer-1 GEMM (128x128), interleaved even/odd
  csr_gemm1_kernel<<<2 * GEMM_BLOCKS + (CSR_BLOCKS - GEMM_BLOCKS), T, 0, stream>>>(
      src, dst, eattr, offs, pk, csr, xb, W1T, bcat1, xc1);

  fused1_kernel<<<(N_NODES + 3) / 4, T, 0, stream>>>(offs, csr, xc1, W1e, att1, bias1, h);

  // layer 2: GEMM [N,256]@[256,128] -> xc2 (BM=64, BN=64: 626 blocks)
  {
    dim3 grid((N_NODES + 63) / 64, 128 / 64);
    gemm_tile_kernel<64, 64><<<grid, T, 0, stream>>>(h, W2T, bcat2, xc2, N_NODES, HC1, 128);
  }
  fused2_kernel<<<(N_NODES + 3) / 4, T, 0, stream>>>(offs, csr, xc2, W2e, att2, bias2, out);
}